// Round 1
// baseline (406.333 us; speedup 1.0000x reference)
//
#include <hip/hip_runtime.h>

// ForwardDeformer: trilinear grid-sample of LBS voxel + dual skinning + 4x4 matmul.
// Shapes (fixed by setup_inputs): B=4, N=250000, J=55, vol [1,55,16,64,64].

#define JNT 55
#define JP  56            // pad channels to multiple of 4 for float4 loads
#define VD  16
#define VH  64
#define VW  64
#define NVOX (VD * VH * VW)   // 65536

// ---------------------------------------------------------------------------
// Pre-pass: vol [J, D, H, W] -> T [D*H*W, JP] (channels-last, padded).
// Reads coalesced across voxel index; each thread writes its own 224 B run.
// ---------------------------------------------------------------------------
__global__ __launch_bounds__(256) void transpose_vol_k(
    const float* __restrict__ vol, float* __restrict__ T)
{
    int v = blockIdx.x * blockDim.x + threadIdx.x;
    if (v >= NVOX) return;
    float vals[JP];
#pragma unroll
    for (int j = 0; j < JNT; ++j) vals[j] = vol[j * NVOX + v];
    vals[JNT] = 0.f;
    float4* dst = (float4*)(T + (size_t)v * JP);
#pragma unroll
    for (int g = 0; g < JP / 4; ++g)
        dst[g] = make_float4(vals[4*g+0], vals[4*g+1], vals[4*g+2], vals[4*g+3]);
}

// ---------------------------------------------------------------------------
// Main kernel: one thread per (b, n). blockIdx.y = b so tfs reads are
// wave-uniform (scalar loads).
// ---------------------------------------------------------------------------
template <bool USE_T>
__global__ __launch_bounds__(256) void deformer_k(
    const float* __restrict__ xc,
    const float* __restrict__ shape_off,
    const float* __restrict__ pose_off,
    const float* __restrict__ tfs,        // [B, J, 4, 4]
    const float* __restrict__ tfs_inv,    // [1, J, 4, 4]
    const float* __restrict__ poseoff_ori,// [1, N, 3]
    const float* __restrict__ lbsw,       // [1, N, J]
    const int*   __restrict__ mask,       // [1, N] (0/1 as int32)
    const float* __restrict__ vol,        // [J, D, H, W] (direct path)
    const float* __restrict__ T,          // [NVOX, JP] (transposed path)
    const float* __restrict__ offk,       // [3]
    const float* __restrict__ sck,        // [3]
    float* __restrict__ out_xd,           // [B, N, 3]
    float* __restrict__ out_w,            // [B, N, 4, 4]
    int N)
{
    int n = blockIdx.x * blockDim.x + threadIdx.x;
    int b = blockIdx.y;
    if (n >= N) return;
    size_t pid = (size_t)b * N + n;
    size_t p3  = pid * 3;

    float x = xc[p3 + 0], y = xc[p3 + 1], z = xc[p3 + 2];

    // normalize -> voxel index space (align_corners=True, border clamp)
    float px = (x + offk[0]) * sck[0];
    float py = (y + offk[1]) * sck[1];
    float pz = (z + offk[2]) * sck[2];
    float ix = fminf(fmaxf((px + 1.f) * 0.5f * (VW - 1), 0.f), (float)(VW - 1));
    float iy = fminf(fmaxf((py + 1.f) * 0.5f * (VH - 1), 0.f), (float)(VH - 1));
    float iz = fminf(fmaxf((pz + 1.f) * 0.5f * (VD - 1), 0.f), (float)(VD - 1));
    float fx = floorf(ix), fy = floorf(iy), fz = floorf(iz);
    float wx = ix - fx,    wy = iy - fy,    wz = iz - fz;
    int x0 = (int)fx, y0 = (int)fy, z0 = (int)fz;
    int x1 = min(x0 + 1, VW - 1);
    int y1 = min(y0 + 1, VH - 1);
    int z1 = min(z0 + 1, VD - 1);

    float w[JP];

    bool m = (mask[n] != 0);
    if (m) {
        // masked points take precomputed lbsw (contiguous 220 B per lane)
        const float* lp = lbsw + (size_t)n * JNT;
#pragma unroll
        for (int j = 0; j < JNT; ++j) w[j] = lp[j];
        w[JNT] = 0.f;
    } else if (USE_T) {
        // channels-last trilinear: 8 corners x 14 float4 contiguous loads
        float cwx[2] = {1.f - wx, wx};
        float cwy[2] = {1.f - wy, wy};
        float cwz[2] = {1.f - wz, wz};
        int   xs[2] = {x0, x1}, ys[2] = {y0, y1}, zs[2] = {z0, z1};
        float4 acc[JP / 4];
#pragma unroll
        for (int g = 0; g < JP / 4; ++g) acc[g] = make_float4(0.f, 0.f, 0.f, 0.f);
#pragma unroll
        for (int cz = 0; cz < 2; ++cz)
#pragma unroll
        for (int cy = 0; cy < 2; ++cy)
#pragma unroll
        for (int cx = 0; cx < 2; ++cx) {
            float cw = cwz[cz] * cwy[cy] * cwx[cx];
            const float4* p =
                (const float4*)(T + (size_t)((zs[cz] * VH + ys[cy]) * VW + xs[cx]) * JP);
#pragma unroll
            for (int g = 0; g < JP / 4; ++g) {
                float4 v = p[g];
                acc[g].x = fmaf(cw, v.x, acc[g].x);
                acc[g].y = fmaf(cw, v.y, acc[g].y);
                acc[g].z = fmaf(cw, v.z, acc[g].z);
                acc[g].w = fmaf(cw, v.w, acc[g].w);
            }
        }
#pragma unroll
        for (int g = 0; g < JP / 4; ++g) {
            w[4*g+0] = acc[g].x; w[4*g+1] = acc[g].y;
            w[4*g+2] = acc[g].z; w[4*g+3] = acc[g].w;
        }
    } else {
        // fallback: gather 8 scalars per channel from native layout
        float w00 = (1.f - wz) * (1.f - wy), w01 = (1.f - wz) * wy;
        float w10 = wz * (1.f - wy),         w11 = wz * wy;
        int o00 = (z0 * VH + y0) * VW, o01 = (z0 * VH + y1) * VW;
        int o10 = (z1 * VH + y0) * VW, o11 = (z1 * VH + y1) * VW;
#pragma unroll
        for (int j = 0; j < JNT; ++j) {
            const float* vp = vol + (size_t)j * NVOX;
            float v000 = vp[o00 + x0], v001 = vp[o00 + x1];
            float v010 = vp[o01 + x0], v011 = vp[o01 + x1];
            float v100 = vp[o10 + x0], v101 = vp[o10 + x1];
            float v110 = vp[o11 + x0], v111 = vp[o11 + x1];
            float c0 = w00 * v000 + w01 * v010 + w10 * v100 + w11 * v110;
            float c1 = w00 * v001 + w01 * v011 + w10 * v101 + w11 * v111;
            w[j] = c0 + wx * (c1 - c0);
        }
        w[JNT] = 0.f;
    }

    // blend matrices: A = sum_j w_j * tfs[b,j], Ai = sum_j w_j * tfs_inv[j]
    float A[16], Ai[16];
#pragma unroll
    for (int i = 0; i < 16; ++i) { A[i] = 0.f; Ai[i] = 0.f; }
    const float* tb = tfs + (size_t)b * JNT * 16;
#pragma unroll
    for (int j = 0; j < JNT; ++j) {
        float wj = w[j];
#pragma unroll
        for (int i = 0; i < 16; ++i) Ai[i] = fmaf(wj, tfs_inv[j * 16 + i], Ai[i]);
#pragma unroll
        for (int i = 0; i < 16; ++i) A[i]  = fmaf(wj, tb[j * 16 + i],      A[i]);
    }

    // first skinning (canonical), offsets, second skinning (posed)
    float c0 = Ai[0]*x + Ai[1]*y + Ai[2]*z  + Ai[3];
    float c1 = Ai[4]*x + Ai[5]*y + Ai[6]*z  + Ai[7];
    float c2 = Ai[8]*x + Ai[9]*y + Ai[10]*z + Ai[11];
    size_t n3 = (size_t)n * 3;
    float sx = c0 - poseoff_ori[n3 + 0] + shape_off[p3 + 0] + pose_off[p3 + 0];
    float sy = c1 - poseoff_ori[n3 + 1] + shape_off[p3 + 1] + pose_off[p3 + 1];
    float sz = c2 - poseoff_ori[n3 + 2] + shape_off[p3 + 2] + pose_off[p3 + 2];
    float d0 = A[0]*sx + A[1]*sy + A[2]*sz  + A[3];
    float d1 = A[4]*sx + A[5]*sy + A[6]*sz  + A[7];
    float d2 = A[8]*sx + A[9]*sy + A[10]*sz + A[11];
    out_xd[p3 + 0] = d0;
    out_xd[p3 + 1] = d1;
    out_xd[p3 + 2] = d2;

    // w_tf_all = A @ Ai, written as 4 coalesced float4 (64 B/lane contiguous)
    float4* ow = (float4*)(out_w + pid * 16);
#pragma unroll
    for (int i = 0; i < 4; ++i) {
        float a0 = A[i*4+0], a1 = A[i*4+1], a2 = A[i*4+2], a3 = A[i*4+3];
        float4 r;
        r.x = a0*Ai[0] + a1*Ai[4] + a2*Ai[8]  + a3*Ai[12];
        r.y = a0*Ai[1] + a1*Ai[5] + a2*Ai[9]  + a3*Ai[13];
        r.z = a0*Ai[2] + a1*Ai[6] + a2*Ai[10] + a3*Ai[14];
        r.w = a0*Ai[3] + a1*Ai[7] + a2*Ai[11] + a3*Ai[15];
        ow[i] = r;
    }
}

extern "C" void kernel_launch(void* const* d_in, const int* in_sizes, int n_in,
                              void* d_out, int out_size, void* d_ws, size_t ws_size,
                              hipStream_t stream)
{
    const float* xc    = (const float*)d_in[0];
    const float* shoff = (const float*)d_in[1];
    const float* pooff = (const float*)d_in[2];
    const float* tfs   = (const float*)d_in[3];
    const float* tfsi  = (const float*)d_in[4];
    const float* poori = (const float*)d_in[5];
    const float* lbsw  = (const float*)d_in[6];
    const int*   mask  = (const int*)d_in[7];
    const float* vol   = (const float*)d_in[8];
    const float* offk  = (const float*)d_in[9];
    const float* sck   = (const float*)d_in[10];

    int N = in_sizes[5] / 3;          // poseoff_ori [1,N,3]
    int B = in_sizes[0] / (3 * N);    // xc [B,N,3]
    float* out_xd = (float*)d_out;
    float* out_w  = (float*)d_out + (size_t)B * N * 3;

    size_t tbytes = (size_t)NVOX * JP * sizeof(float);
    float* T = (float*)d_ws;
    bool use_t = (ws_size >= tbytes);

    dim3 blk(256);
    dim3 grd((N + 255) / 256, B);

    if (use_t) {
        transpose_vol_k<<<dim3((NVOX + 255) / 256), blk, 0, stream>>>(vol, T);
        deformer_k<true><<<grd, blk, 0, stream>>>(
            xc, shoff, pooff, tfs, tfsi, poori, lbsw, mask, vol, T, offk, sck,
            out_xd, out_w, N);
    } else {
        deformer_k<false><<<grd, blk, 0, stream>>>(
            xc, shoff, pooff, tfs, tfsi, poori, lbsw, mask, vol, T, offk, sck,
            out_xd, out_w, N);
    }
}

// Round 2
// 335.269 us; speedup vs baseline: 1.2120x; 1.2120x over previous
//
#include <hip/hip_runtime.h>

// ForwardDeformer: trilinear grid-sample of LBS voxel + dual skinning + 4x4 matmul.
// Shapes (fixed): B=4, N=250000, J=55, vol [1,55,16,64,64].
//
// Key structural choice (R1): blending is linear, so pre-blend the voxel grid
// with the transform matrices ONCE per call:
//   Mi_tab[v]   = sum_j vol[j,v] * tfs_inv[j]        (batch-independent)
//   Mv_tab[b,v] = sum_j vol[j,v] * tfs[b,j]
// Then per point: A = sum_{8 corners} cw_c * Mv_tab[b,c], same for Ai.
// This removes the per-thread w[56] array that spilled to scratch in R0
// (VGPR=64 + 278MB FETCH = spill traffic, latency-bound at 15% VALU/16% HBM).

#define JNT 55
#define VD  16
#define VH  64
#define VW  64
#define NVOX (VD * VH * VW)   // 65536

// ---------------------------------------------------------------------------
// Pre-pass: blend voxel weights with matrices.
// One thread per voxel; vol reads coalesced (lane-contiguous in v).
// ---------------------------------------------------------------------------
__global__ __launch_bounds__(256, 1) void build_mats_k(
    const float* __restrict__ vol,      // [J, NVOX]
    const float* __restrict__ tfs,      // [B, J, 16]
    const float* __restrict__ tfs_inv,  // [J, 16]
    float* __restrict__ Mi_tab,         // [NVOX, 16]
    float* __restrict__ Mv_tab,         // [B, NVOX, 16]
    int B)
{
    int v = blockIdx.x * blockDim.x + threadIdx.x;
    if (v >= NVOX) return;
    float w[JNT];
#pragma unroll
    for (int j = 0; j < JNT; ++j) w[j] = vol[j * NVOX + v];

    float M[16];
#pragma unroll
    for (int i = 0; i < 16; ++i) M[i] = 0.f;
#pragma unroll
    for (int j = 0; j < JNT; ++j) {
        float wj = w[j];
#pragma unroll
        for (int i = 0; i < 16; ++i) M[i] = fmaf(wj, tfs_inv[j * 16 + i], M[i]);
    }
    float4* dst = (float4*)(Mi_tab + (size_t)v * 16);
#pragma unroll
    for (int g = 0; g < 4; ++g)
        dst[g] = make_float4(M[4*g+0], M[4*g+1], M[4*g+2], M[4*g+3]);

    for (int b = 0; b < B; ++b) {
        const float* tb = tfs + (size_t)b * JNT * 16;
#pragma unroll
        for (int i = 0; i < 16; ++i) M[i] = 0.f;
#pragma unroll
        for (int j = 0; j < JNT; ++j) {
            float wj = w[j];
#pragma unroll
            for (int i = 0; i < 16; ++i) M[i] = fmaf(wj, tb[j * 16 + i], M[i]);
        }
        float4* dv = (float4*)(Mv_tab + ((size_t)b * NVOX + v) * 16);
#pragma unroll
        for (int g = 0; g < 4; ++g)
            dv[g] = make_float4(M[4*g+0], M[4*g+1], M[4*g+2], M[4*g+3]);
    }
}

// ---------------------------------------------------------------------------
// Main kernel: one thread per (b, n). blockIdx.y = b (tfs base wave-uniform).
// Unmasked: interpolate 8 pre-blended matrices (64 float4 gathers, 256 FMA).
// Masked: blend from lbsw with w_j consumed immediately (no array).
// ---------------------------------------------------------------------------
template <bool USE_TAB>
__global__ __launch_bounds__(256, 4) void deformer_k(
    const float* __restrict__ xc,
    const float* __restrict__ shape_off,
    const float* __restrict__ pose_off,
    const float* __restrict__ tfs,        // [B, J, 16]
    const float* __restrict__ tfs_inv,    // [J, 16]
    const float* __restrict__ poseoff_ori,// [N, 3]
    const float* __restrict__ lbsw,       // [N, J]
    const int*   __restrict__ mask,       // [N]
    const float* __restrict__ vol,        // [J, NVOX] (fallback path)
    const float* __restrict__ Mi_tab,     // [NVOX, 16]
    const float* __restrict__ Mv_tab,     // [B, NVOX, 16]
    const float* __restrict__ offk,       // [3]
    const float* __restrict__ sck,        // [3]
    float* __restrict__ out_xd,           // [B, N, 3]
    float* __restrict__ out_w,            // [B, N, 16]
    int N)
{
    int n = blockIdx.x * blockDim.x + threadIdx.x;
    int b = blockIdx.y;
    if (n >= N) return;
    size_t pid = (size_t)b * N + n;
    size_t p3  = pid * 3;

    float x = xc[p3 + 0], y = xc[p3 + 1], z = xc[p3 + 2];

    float A[16], Ai[16];
#pragma unroll
    for (int i = 0; i < 16; ++i) { A[i] = 0.f; Ai[i] = 0.f; }

    bool m = (mask[n] != 0);
    if (m) {
        // w = lbsw[n]; blend directly, one w_j at a time (no w array).
        const float* lp = lbsw + (size_t)n * JNT;
        const float* tb = tfs + (size_t)b * JNT * 16;
#pragma unroll
        for (int j = 0; j < JNT; ++j) {
            float wj = lp[j];
#pragma unroll
            for (int i = 0; i < 16; ++i) Ai[i] = fmaf(wj, tfs_inv[j * 16 + i], Ai[i]);
#pragma unroll
            for (int i = 0; i < 16; ++i) A[i]  = fmaf(wj, tb[j * 16 + i],      A[i]);
        }
    } else {
        // grid_sample coords (align_corners=True, border clamp)
        float px = (x + offk[0]) * sck[0];
        float py = (y + offk[1]) * sck[1];
        float pz = (z + offk[2]) * sck[2];
        float ix = fminf(fmaxf((px + 1.f) * 0.5f * (VW - 1), 0.f), (float)(VW - 1));
        float iy = fminf(fmaxf((py + 1.f) * 0.5f * (VH - 1), 0.f), (float)(VH - 1));
        float iz = fminf(fmaxf((pz + 1.f) * 0.5f * (VD - 1), 0.f), (float)(VD - 1));
        float fx = floorf(ix), fy = floorf(iy), fz = floorf(iz);
        float wx = ix - fx,    wy = iy - fy,    wz = iz - fz;
        int x0 = (int)fx, y0 = (int)fy, z0 = (int)fz;
        int x1 = min(x0 + 1, VW - 1);
        int y1 = min(y0 + 1, VH - 1);
        int z1 = min(z0 + 1, VD - 1);

        if (USE_TAB) {
            float cwx[2] = {1.f - wx, wx};
            float cwy[2] = {1.f - wy, wy};
            float cwz[2] = {1.f - wz, wz};
            int   xs[2] = {x0, x1}, ys[2] = {y0, y1}, zs[2] = {z0, z1};
            const float* Mvb = Mv_tab + (size_t)b * NVOX * 16;
#pragma unroll
            for (int cz = 0; cz < 2; ++cz)
#pragma unroll
            for (int cy = 0; cy < 2; ++cy)
#pragma unroll
            for (int cx = 0; cx < 2; ++cx) {
                float cw = cwz[cz] * cwy[cy] * cwx[cx];
                size_t vox = (size_t)(zs[cz] * VH + ys[cy]) * VW + xs[cx];
                const float4* pi = (const float4*)(Mi_tab + vox * 16);
                const float4* pv = (const float4*)(Mvb    + vox * 16);
#pragma unroll
                for (int g = 0; g < 4; ++g) {
                    float4 mi = pi[g];
                    Ai[4*g+0] = fmaf(cw, mi.x, Ai[4*g+0]);
                    Ai[4*g+1] = fmaf(cw, mi.y, Ai[4*g+1]);
                    Ai[4*g+2] = fmaf(cw, mi.z, Ai[4*g+2]);
                    Ai[4*g+3] = fmaf(cw, mi.w, Ai[4*g+3]);
                }
#pragma unroll
                for (int g = 0; g < 4; ++g) {
                    float4 mv = pv[g];
                    A[4*g+0] = fmaf(cw, mv.x, A[4*g+0]);
                    A[4*g+1] = fmaf(cw, mv.y, A[4*g+1]);
                    A[4*g+2] = fmaf(cw, mv.z, A[4*g+2]);
                    A[4*g+3] = fmaf(cw, mv.w, A[4*g+3]);
                }
            }
        } else {
            // fallback (ws too small): per-channel 8-corner gather, blend fused
            float w00 = (1.f - wz) * (1.f - wy), w01 = (1.f - wz) * wy;
            float w10 = wz * (1.f - wy),         w11 = wz * wy;
            int o00 = (z0 * VH + y0) * VW, o01 = (z0 * VH + y1) * VW;
            int o10 = (z1 * VH + y0) * VW, o11 = (z1 * VH + y1) * VW;
            const float* tb = tfs + (size_t)b * JNT * 16;
#pragma unroll
            for (int j = 0; j < JNT; ++j) {
                const float* vp = vol + (size_t)j * NVOX;
                float v000 = vp[o00 + x0], v001 = vp[o00 + x1];
                float v010 = vp[o01 + x0], v011 = vp[o01 + x1];
                float v100 = vp[o10 + x0], v101 = vp[o10 + x1];
                float v110 = vp[o11 + x0], v111 = vp[o11 + x1];
                float c0 = w00 * v000 + w01 * v010 + w10 * v100 + w11 * v110;
                float c1 = w00 * v001 + w01 * v011 + w10 * v101 + w11 * v111;
                float wj = c0 + wx * (c1 - c0);
#pragma unroll
                for (int i = 0; i < 16; ++i) Ai[i] = fmaf(wj, tfs_inv[j*16+i], Ai[i]);
#pragma unroll
                for (int i = 0; i < 16; ++i) A[i]  = fmaf(wj, tb[j*16+i],      A[i]);
            }
        }
    }

    // first skinning (canonical), offsets, second skinning (posed)
    float c0 = Ai[0]*x + Ai[1]*y + Ai[2]*z  + Ai[3];
    float c1 = Ai[4]*x + Ai[5]*y + Ai[6]*z  + Ai[7];
    float c2 = Ai[8]*x + Ai[9]*y + Ai[10]*z + Ai[11];
    size_t n3 = (size_t)n * 3;
    float sx = c0 - poseoff_ori[n3 + 0] + shape_off[p3 + 0] + pose_off[p3 + 0];
    float sy = c1 - poseoff_ori[n3 + 1] + shape_off[p3 + 1] + pose_off[p3 + 1];
    float sz = c2 - poseoff_ori[n3 + 2] + shape_off[p3 + 2] + pose_off[p3 + 2];
    float d0 = A[0]*sx + A[1]*sy + A[2]*sz  + A[3];
    float d1 = A[4]*sx + A[5]*sy + A[6]*sz  + A[7];
    float d2 = A[8]*sx + A[9]*sy + A[10]*sz + A[11];
    out_xd[p3 + 0] = d0;
    out_xd[p3 + 1] = d1;
    out_xd[p3 + 2] = d2;

    // w_tf_all = A @ Ai, 4 coalesced float4 per lane
    float4* ow = (float4*)(out_w + pid * 16);
#pragma unroll
    for (int i = 0; i < 4; ++i) {
        float a0 = A[i*4+0], a1 = A[i*4+1], a2 = A[i*4+2], a3 = A[i*4+3];
        float4 r;
        r.x = a0*Ai[0] + a1*Ai[4] + a2*Ai[8]  + a3*Ai[12];
        r.y = a0*Ai[1] + a1*Ai[5] + a2*Ai[9]  + a3*Ai[13];
        r.z = a0*Ai[2] + a1*Ai[6] + a2*Ai[10] + a3*Ai[14];
        r.w = a0*Ai[3] + a1*Ai[7] + a2*Ai[11] + a3*Ai[15];
        ow[i] = r;
    }
}

extern "C" void kernel_launch(void* const* d_in, const int* in_sizes, int n_in,
                              void* d_out, int out_size, void* d_ws, size_t ws_size,
                              hipStream_t stream)
{
    const float* xc    = (const float*)d_in[0];
    const float* shoff = (const float*)d_in[1];
    const float* pooff = (const float*)d_in[2];
    const float* tfs   = (const float*)d_in[3];
    const float* tfsi  = (const float*)d_in[4];
    const float* poori = (const float*)d_in[5];
    const float* lbsw  = (const float*)d_in[6];
    const int*   mask  = (const int*)d_in[7];
    const float* vol   = (const float*)d_in[8];
    const float* offk  = (const float*)d_in[9];
    const float* sck   = (const float*)d_in[10];

    int N = in_sizes[5] / 3;          // poseoff_ori [1,N,3]
    int B = in_sizes[0] / (3 * N);    // xc [B,N,3]
    float* out_xd = (float*)d_out;
    float* out_w  = (float*)d_out + (size_t)B * N * 3;

    size_t tbytes = (size_t)NVOX * 16 * (1 + B) * sizeof(float);
    float* Mi_tab = (float*)d_ws;
    float* Mv_tab = Mi_tab + (size_t)NVOX * 16;
    bool use_tab = (ws_size >= tbytes);

    dim3 blk(256);
    dim3 grd((N + 255) / 256, B);

    if (use_tab) {
        build_mats_k<<<dim3((NVOX + 255) / 256), blk, 0, stream>>>(
            vol, tfs, tfsi, Mi_tab, Mv_tab, B);
        deformer_k<true><<<grd, blk, 0, stream>>>(
            xc, shoff, pooff, tfs, tfsi, poori, lbsw, mask, vol, Mi_tab, Mv_tab,
            offk, sck, out_xd, out_w, N);
    } else {
        deformer_k<false><<<grd, blk, 0, stream>>>(
            xc, shoff, pooff, tfs, tfsi, poori, lbsw, mask, vol, Mi_tab, Mv_tab,
            offk, sck, out_xd, out_w, N);
    }
}